// Round 9
// baseline (66.217 us; speedup 1.0000x reference)
//
#include <hip/hip_runtime.h>
#include <hip/hip_bf16.h>
#include <stdint.h>

#define N_ROWS 4096
#define D_DIM  256
#define TWO_N  8192
#define ROWB   512                       // bytes per bf16 row
#define C_EXP  2.8853900817779268f       // 2*log2(e): exp(2*dot)=2^(dot*2*log2e)

typedef __attribute__((ext_vector_type(8))) short short8;
typedef __attribute__((ext_vector_type(16))) float f32x16;

__device__ __forceinline__ unsigned bf16rne(float f) {
    unsigned u = __float_as_uint(f);
    return (u + 0x7fffu + ((u >> 16) & 1u)) >> 16;
}
__device__ __forceinline__ float bf16val(unsigned bits) {
    return __uint_as_float(bits << 16);
}

// ---------- K1: normalize -> bf16 reps, exact pos-pair sims, bf16 self-dot exp, zero rowsum ----------
__global__ __launch_bounds__(256) void kprep(const float* __restrict__ zi,
                                             const float* __restrict__ zj,
                                             unsigned short* __restrict__ reps,
                                             float* __restrict__ pos,
                                             float* __restrict__ selfexp,
                                             float* __restrict__ rowsum) {
    int wave = threadIdx.x >> 6, lane = threadIdx.x & 63;
    int k = blockIdx.x * 4 + wave;   // 0..4095
    float4 a = *(const float4*)(zi + (size_t)k * D_DIM + lane * 4);
    float4 b = *(const float4*)(zj + (size_t)k * D_DIM + lane * 4);
    float dii = a.x * a.x + a.y * a.y + a.z * a.z + a.w * a.w;
    float djj = b.x * b.x + b.y * b.y + b.z * b.z + b.w * b.w;
    float dij = a.x * b.x + a.y * b.y + a.z * b.z + a.w * b.w;
#pragma unroll
    for (int m = 1; m < 64; m <<= 1) {
        dii += __shfl_xor(dii, m, 64);
        djj += __shfl_xor(djj, m, 64);
        dij += __shfl_xor(dij, m, 64);
    }
    float si = 1.0f / fmaxf(sqrtf(dii), 1e-12f);
    float sj = 1.0f / fmaxf(sqrtf(djj), 1e-12f);

    unsigned a0 = bf16rne(a.x * si), a1 = bf16rne(a.y * si);
    unsigned a2 = bf16rne(a.z * si), a3 = bf16rne(a.w * si);
    unsigned b0 = bf16rne(b.x * sj), b1 = bf16rne(b.y * sj);
    unsigned b2 = bf16rne(b.z * sj), b3 = bf16rne(b.w * sj);
    {
        uint2 o; o.x = a0 | (a1 << 16); o.y = a2 | (a3 << 16);
        *(uint2*)(reps + (size_t)k * D_DIM + lane * 4) = o;
    }
    {
        uint2 o; o.x = b0 | (b1 << 16); o.y = b2 | (b3 << 16);
        *(uint2*)(reps + (size_t)(k + N_ROWS) * D_DIM + lane * 4) = o;
    }
    float fa0 = bf16val(a0), fa1 = bf16val(a1), fa2 = bf16val(a2), fa3 = bf16val(a3);
    float fb0 = bf16val(b0), fb1 = bf16val(b1), fb2 = bf16val(b2), fb3 = bf16val(b3);
    float sa = fa0 * fa0 + fa1 * fa1 + fa2 * fa2 + fa3 * fa3;
    float sb = fb0 * fb0 + fb1 * fb1 + fb2 * fb2 + fb3 * fb3;
#pragma unroll
    for (int m = 1; m < 64; m <<= 1) {
        sa += __shfl_xor(sa, m, 64);
        sb += __shfl_xor(sb, m, 64);
    }
    if (lane == 0) {
        float p = dij * si * sj * 2.0f;   // /TEMPERATURE
        pos[k] = p;
        pos[k + N_ROWS] = p;
        selfexp[k] = __builtin_amdgcn_exp2f(sa * C_EXP);
        selfexp[k + N_ROWS] = __builtin_amdgcn_exp2f(sb * C_EXP);
    }
    if (threadIdx.x < 8) rowsum[blockIdx.x * 8 + threadIdx.x] = 0.0f;
}

// ---------- K2: 2x2 wave grid (64 rows x 32 cols per wave), 32x32x16 MFMA ----------
// Grid 1024 = 64 rt (BM=128) x 16 cs (512 cols = 8 tiles of 64). L2-safe XCD patch (R8).
// Waves split M AND N: FLOP per LDS-read-byte = 64 (was 32) -> LDS floor halves.
// A: 64 rows full-K in regs (128 VGPR). B: 64-col K=256 tiles in LDS (32KB, XOR slot
// swizzle, R1-verbatim staging). One __syncthreads pair per tile. launch_bounds(256,2).
// Uniform epilogue; diagonal self-term subtracted later via selfexp.
__global__ __launch_bounds__(256, 2) void kmain(const unsigned short* __restrict__ reps,
                                                float* __restrict__ rowsum) {
    __shared__ __align__(16) char ldsB[64 * 512];   // 32 KiB

    const int tid = threadIdx.x;
    const int wave = tid >> 6, lane = tid & 63;
    const int l31 = lane & 31, lhi = lane >> 5, x7 = l31 & 7;
    const int mg = wave >> 1, ng = wave & 1;

    // 2D XCD patch decode (R8 verbatim): per-XCD footprint A 1MB + B 2MB < 4MB L2
    const int xcd = blockIdx.x & 7;
    const int local = blockIdx.x >> 3;          // 0..127
    const int rt = (xcd >> 1) * 16 + (local & 15);
    const int cs = (xcd & 1) * 8 + (local >> 4);

    const int rowbase = rt * 128 + mg * 64;     // this wave's 64-row band
    const char* repsb = (const char*)reps;

    // A fragments: 2 row-frags (32 rows each) x 16 k-steps, 128 VGPR (R2-verified layout)
    short8 afrag[2][16];
#pragma unroll
    for (int rf = 0; rf < 2; ++rf) {
        const char* ar = repsb + (size_t)(rowbase + rf * 32 + l31) * ROWB + lhi * 16;
#pragma unroll
        for (int ks = 0; ks < 16; ++ks)
            afrag[rf][ks] = *(const short8*)(ar + ks * 32);
    }

    float rsum[2][16];
#pragma unroll
    for (int rf = 0; rf < 2; ++rf)
#pragma unroll
        for (int r = 0; r < 16; ++r) rsum[rf][r] = 0.0f;

    const int cbase = (ng * 32 + l31) * ROWB;   // this wave's B col (LDS byte base)

    for (int ct = 0; ct < 8; ++ct) {
        const int colbase = cs * 512 + ct * 64;

        // stage B tile [64 cols][512 B] with slot XOR-swizzle  (R1 verbatim)
#pragma unroll
        for (int i = 0; i < 8; ++i) {
            int o = tid * 16 + i * 4096;
            int row = o >> 9;
            int slot = (o >> 4) & 31;
            uint4 v = *(const uint4*)(repsb + (size_t)(colbase + row) * ROWB + slot * 16);
            int dslot = slot ^ (row & 7);
            *(uint4*)(ldsB + row * 512 + dslot * 16) = v;
        }
        __syncthreads();

        f32x16 acc0, acc1;
#pragma unroll
        for (int r = 0; r < 16; ++r) { acc0[r] = 0.0f; acc1[r] = 0.0f; }

#pragma unroll
        for (int ks = 0; ks < 16; ++ks) {
            int ds = ((2 * ks + lhi) ^ x7) << 4;
            short8 b = *(const short8*)(ldsB + cbase + ds);
            acc0 = __builtin_amdgcn_mfma_f32_32x32x16_bf16(afrag[0][ks], b, acc0, 0, 0, 0);
            acc1 = __builtin_amdgcn_mfma_f32_32x32x16_bf16(afrag[1][ks], b, acc1, 0, 0, 0);
        }
        __syncthreads();

        // uniform epilogue: exp + row-partial accumulate (no diag branch)
#pragma unroll
        for (int r = 0; r < 16; ++r) {
            rsum[0][r] += __builtin_amdgcn_exp2f(acc0[r] * C_EXP);
            rsum[1][r] += __builtin_amdgcn_exp2f(acc1[r] * C_EXP);
        }
    }

    // row-partials: reduce 32 lanes sharing each row (R2-verified mapping), 1 atomic/row
#pragma unroll
    for (int rf = 0; rf < 2; ++rf)
#pragma unroll
        for (int r = 0; r < 16; ++r) {
            float s = rsum[rf][r];
            s += __shfl_xor(s, 1, 64);
            s += __shfl_xor(s, 2, 64);
            s += __shfl_xor(s, 4, 64);
            s += __shfl_xor(s, 8, 64);
            s += __shfl_xor(s, 16, 64);
            if (l31 == 0)
                atomicAdd(&rowsum[rowbase + rf * 32 + (r & 3) + 8 * (r >> 2) + 4 * lhi], s);
        }
}

// ---------- K3: loss = mean(log(rowsum - selfexp) - pos) ----------
__global__ __launch_bounds__(1024) void kfinal(const float* __restrict__ rowsum,
                                               const float* __restrict__ pos,
                                               const float* __restrict__ selfexp,
                                               float* __restrict__ out) {
    __shared__ float red[16];
    float local = 0.0f;
    for (int r = threadIdx.x; r < TWO_N; r += 1024)
        local += __builtin_amdgcn_logf(rowsum[r] - selfexp[r]) * 0.6931471805599453f - pos[r];
#pragma unroll
    for (int m = 1; m < 64; m <<= 1) local += __shfl_xor(local, m, 64);
    if ((threadIdx.x & 63) == 0) red[threadIdx.x >> 6] = local;
    __syncthreads();
    if (threadIdx.x == 0) {
        float t = 0.0f;
#pragma unroll
        for (int i = 0; i < 16; ++i) t += red[i];
        out[0] = t * (1.0f / (float)TWO_N);
    }
}

extern "C" void kernel_launch(void* const* d_in, const int* in_sizes, int n_in,
                              void* d_out, int out_size, void* d_ws, size_t ws_size,
                              hipStream_t stream) {
    const float* zi = (const float*)d_in[0];
    const float* zj = (const float*)d_in[1];
    float* out = (float*)d_out;

    unsigned short* reps = (unsigned short*)d_ws;                       // 4 MiB
    float* rowsum = (float*)((char*)d_ws + (size_t)TWO_N * D_DIM * 2);  // 32 KiB
    float* pos = rowsum + TWO_N;                                        // 32 KiB
    float* selfexp = pos + TWO_N;                                       // 32 KiB

    kprep<<<1024, 256, 0, stream>>>(zi, zj, reps, pos, selfexp, rowsum);
    kmain<<<1024, 256, 0, stream>>>(reps, rowsum);
    kfinal<<<1, 1024, 0, stream>>>(rowsum, pos, selfexp, out);
}

// Round 10
// 53.891 us; speedup vs baseline: 1.2287x; 1.2287x over previous
//
#include <hip/hip_runtime.h>
#include <hip/hip_bf16.h>
#include <stdint.h>

#define N_ROWS 4096
#define D_DIM  256
#define TWO_N  8192
#define ROWB   512                       // bytes per bf16 row
#define C_EXP  2.8853900817779268f       // 2*log2(e): exp(2*dot)=2^(dot*2*log2e)

typedef __attribute__((ext_vector_type(8))) short short8;
typedef __attribute__((ext_vector_type(4))) float f32x4;

__device__ __forceinline__ unsigned bf16rne(float f) {
    unsigned u = __float_as_uint(f);
    return (u + 0x7fffu + ((u >> 16) & 1u)) >> 16;
}
__device__ __forceinline__ float bf16val(unsigned bits) {
    return __uint_as_float(bits << 16);
}

// ---------- K1: normalize -> bf16 reps, exact pos-pair sims, bf16 self-dot exp, zero rowsum ----------
__global__ __launch_bounds__(256) void kprep(const float* __restrict__ zi,
                                             const float* __restrict__ zj,
                                             unsigned short* __restrict__ reps,
                                             float* __restrict__ pos,
                                             float* __restrict__ selfexp,
                                             float* __restrict__ rowsum) {
    int wave = threadIdx.x >> 6, lane = threadIdx.x & 63;
    int k = blockIdx.x * 4 + wave;   // 0..4095
    float4 a = *(const float4*)(zi + (size_t)k * D_DIM + lane * 4);
    float4 b = *(const float4*)(zj + (size_t)k * D_DIM + lane * 4);
    float dii = a.x * a.x + a.y * a.y + a.z * a.z + a.w * a.w;
    float djj = b.x * b.x + b.y * b.y + b.z * b.z + b.w * b.w;
    float dij = a.x * b.x + a.y * b.y + a.z * b.z + a.w * b.w;
#pragma unroll
    for (int m = 1; m < 64; m <<= 1) {
        dii += __shfl_xor(dii, m, 64);
        djj += __shfl_xor(djj, m, 64);
        dij += __shfl_xor(dij, m, 64);
    }
    float si = 1.0f / fmaxf(sqrtf(dii), 1e-12f);
    float sj = 1.0f / fmaxf(sqrtf(djj), 1e-12f);

    unsigned a0 = bf16rne(a.x * si), a1 = bf16rne(a.y * si);
    unsigned a2 = bf16rne(a.z * si), a3 = bf16rne(a.w * si);
    unsigned b0 = bf16rne(b.x * sj), b1 = bf16rne(b.y * sj);
    unsigned b2 = bf16rne(b.z * sj), b3 = bf16rne(b.w * sj);
    {
        uint2 o; o.x = a0 | (a1 << 16); o.y = a2 | (a3 << 16);
        *(uint2*)(reps + (size_t)k * D_DIM + lane * 4) = o;
    }
    {
        uint2 o; o.x = b0 | (b1 << 16); o.y = b2 | (b3 << 16);
        *(uint2*)(reps + (size_t)(k + N_ROWS) * D_DIM + lane * 4) = o;
    }
    float fa0 = bf16val(a0), fa1 = bf16val(a1), fa2 = bf16val(a2), fa3 = bf16val(a3);
    float fb0 = bf16val(b0), fb1 = bf16val(b1), fb2 = bf16val(b2), fb3 = bf16val(b3);
    float sa = fa0 * fa0 + fa1 * fa1 + fa2 * fa2 + fa3 * fa3;
    float sb = fb0 * fb0 + fb1 * fb1 + fb2 * fb2 + fb3 * fb3;
#pragma unroll
    for (int m = 1; m < 64; m <<= 1) {
        sa += __shfl_xor(sa, m, 64);
        sb += __shfl_xor(sb, m, 64);
    }
    if (lane == 0) {
        float p = dij * si * sj * 2.0f;   // /TEMPERATURE
        pos[k] = p;
        pos[k + N_ROWS] = p;
        selfexp[k] = __builtin_amdgcn_exp2f(sa * C_EXP);
        selfexp[k + N_ROWS] = __builtin_amdgcn_exp2f(sb * C_EXP);
    }
    if (threadIdx.x < 8) rowsum[blockIdx.x * 8 + threadIdx.x] = 0.0f;
}

// ---------- K2: R8 structure, spill-free (no VGPR cap) ----------
// Grid 1024 = 64 row-tiles (BM=128) x 16 col-splits (512 cols = 8 tiles of 64).
// L2-safe 2D XCD patch: each XCD owns 16rt x 8cs -> A 1MB + B 2MB < 4MB L2.
// 4 waves x 32 rows; 16x16x32 MFMA, 2 A-frags x 4 B-frags; reg-staged LDS B-tiles
// (XOR slot swizzle); plain __syncthreads pair per tile (R1-verbatim loop).
// launch_bounds(256) ONLY: natural VGPR ~100-110 (R7/R8/R9's min-waves caps caused
// silent scratch spills: VGPR 64 + WRITE_SIZE 16-47MB). ~110 VGPR still allows
// 4 waves/SIMD + 4 blocks/CU (LDS 128<=160KB).
__global__ __launch_bounds__(256) void kmain(const unsigned short* __restrict__ reps,
                                             float* __restrict__ rowsum) {
    __shared__ __align__(16) char ldsB[64 * 512];   // 32 KiB

    const int tid = threadIdx.x;
    const int wave = tid >> 6, lane = tid & 63;
    const int l15 = lane & 15, lhi = lane >> 4;

    // 2D XCD patch decode: xcd = bid&7 owns rt in [(xcd>>1)*16,+16), cs in [(xcd&1)*8,+8)
    const int xcd = blockIdx.x & 7;
    const int local = blockIdx.x >> 3;          // 0..127
    const int rt = (xcd >> 1) * 16 + (local & 15);
    const int cs = (xcd & 1) * 8 + (local >> 4);

    const int rowbaseW = rt * 128 + wave * 32;
    const char* repsb = (const char*)reps;

    // A fragments: 2 row-frags x 8 k-steps, 16B each  (R1 verbatim)
    short8 afrag[2][8];
#pragma unroll
    for (int rf = 0; rf < 2; ++rf) {
        const char* arow = repsb + (size_t)(rowbaseW + rf * 16 + l15) * ROWB;
#pragma unroll
        for (int ks = 0; ks < 8; ++ks)
            afrag[rf][ks] = *(const short8*)(arow + ks * 64 + lhi * 16);
    }

    float rsum[2][4];
#pragma unroll
    for (int rf = 0; rf < 2; ++rf)
#pragma unroll
        for (int r = 0; r < 4; ++r) rsum[rf][r] = 0.0f;

    for (int ct = 0; ct < 8; ++ct) {
        const int colbase = cs * 512 + ct * 64;

        // stage B tile [64 cols][512 B] with slot XOR-swizzle  (R1 verbatim)
#pragma unroll
        for (int i = 0; i < 8; ++i) {
            int o = tid * 16 + i * 4096;
            int row = o >> 9;
            int slot = (o >> 4) & 31;
            uint4 v = *(const uint4*)(repsb + (size_t)(colbase + row) * ROWB + slot * 16);
            int dslot = slot ^ (row & 7);
            *(uint4*)(ldsB + row * 512 + dslot * 16) = v;
        }
        __syncthreads();

        f32x4 acc[2][4];
#pragma unroll
        for (int rf = 0; rf < 2; ++rf)
#pragma unroll
            for (int cf = 0; cf < 4; ++cf) acc[rf][cf] = (f32x4){0.f, 0.f, 0.f, 0.f};

#pragma unroll
        for (int ks = 0; ks < 8; ++ks) {
            short8 bfr[4];
#pragma unroll
            for (int cf = 0; cf < 4; ++cf) {
                int col = cf * 16 + l15;
                int slot = ks * 4 + lhi;
                int ds = slot ^ (col & 7);
                bfr[cf] = *(const short8*)(ldsB + col * 512 + ds * 16);
            }
#pragma unroll
            for (int rf = 0; rf < 2; ++rf)
#pragma unroll
                for (int cf = 0; cf < 4; ++cf)
                    acc[rf][cf] = __builtin_amdgcn_mfma_f32_16x16x32_bf16(
                        afrag[rf][ks], bfr[cf], acc[rf][cf], 0, 0, 0);
        }
        __syncthreads();

        // uniform epilogue: exp + row-partial accumulate (no diag branch)
#pragma unroll
        for (int rf = 0; rf < 2; ++rf)
#pragma unroll
            for (int cf = 0; cf < 4; ++cf) {
                f32x4 cv = acc[rf][cf];
#pragma unroll
                for (int r = 0; r < 4; ++r)
                    rsum[rf][r] += __builtin_amdgcn_exp2f(cv[r] * C_EXP);
            }
    }

    // row-partials: reduce 16 lanes sharing each row, one atomic per row  (R1 verbatim)
#pragma unroll
    for (int rf = 0; rf < 2; ++rf)
#pragma unroll
        for (int r = 0; r < 4; ++r) {
            float s = rsum[rf][r];
            s += __shfl_xor(s, 1, 64);
            s += __shfl_xor(s, 2, 64);
            s += __shfl_xor(s, 4, 64);
            s += __shfl_xor(s, 8, 64);
            if (l15 == 0)
                atomicAdd(&rowsum[rowbaseW + rf * 16 + lhi * 4 + r], s);
        }
}

// ---------- K3: loss = mean(log(rowsum - selfexp) - pos) ----------
__global__ __launch_bounds__(1024) void kfinal(const float* __restrict__ rowsum,
                                               const float* __restrict__ pos,
                                               const float* __restrict__ selfexp,
                                               float* __restrict__ out) {
    __shared__ float red[16];
    float local = 0.0f;
    for (int r = threadIdx.x; r < TWO_N; r += 1024)
        local += __builtin_amdgcn_logf(rowsum[r] - selfexp[r]) * 0.6931471805599453f - pos[r];
#pragma unroll
    for (int m = 1; m < 64; m <<= 1) local += __shfl_xor(local, m, 64);
    if ((threadIdx.x & 63) == 0) red[threadIdx.x >> 6] = local;
    __syncthreads();
    if (threadIdx.x == 0) {
        float t = 0.0f;
#pragma unroll
        for (int i = 0; i < 16; ++i) t += red[i];
        out[0] = t * (1.0f / (float)TWO_N);
    }
}

extern "C" void kernel_launch(void* const* d_in, const int* in_sizes, int n_in,
                              void* d_out, int out_size, void* d_ws, size_t ws_size,
                              hipStream_t stream) {
    const float* zi = (const float*)d_in[0];
    const float* zj = (const float*)d_in[1];
    float* out = (float*)d_out;

    unsigned short* reps = (unsigned short*)d_ws;                       // 4 MiB
    float* rowsum = (float*)((char*)d_ws + (size_t)TWO_N * D_DIM * 2);  // 32 KiB
    float* pos = rowsum + TWO_N;                                        // 32 KiB
    float* selfexp = pos + TWO_N;                                       // 32 KiB

    kprep<<<1024, 256, 0, stream>>>(zi, zj, reps, pos, selfexp, rowsum);
    kmain<<<1024, 256, 0, stream>>>(reps, rowsum);
    kfinal<<<1, 1024, 0, stream>>>(rowsum, pos, selfexp, out);
}

// Round 11
// 45.114 us; speedup vs baseline: 1.4678x; 1.1946x over previous
//
#include <hip/hip_runtime.h>
#include <hip/hip_bf16.h>
#include <stdint.h>

#define N_ROWS 4096
#define D_DIM  256
#define TWO_N  8192
#define ROWB   512                       // bytes per bf16 row
#define C_EXP  2.8853900817779268f       // 2*log2(e): exp(2*dot)=2^(dot*2*log2e)

typedef __attribute__((ext_vector_type(8))) short short8;
typedef __attribute__((ext_vector_type(4))) float f32x4;

__device__ __forceinline__ unsigned bf16rne(float f) {
    unsigned u = __float_as_uint(f);
    return (u + 0x7fffu + ((u >> 16) & 1u)) >> 16;
}
__device__ __forceinline__ float bf16val(unsigned bits) {
    return __uint_as_float(bits << 16);
}

// ---------- K1: normalize -> bf16 reps, exact pos-pair sims, bf16 self-dot exp, zero rowsum ----------
__global__ __launch_bounds__(256) void kprep(const float* __restrict__ zi,
                                             const float* __restrict__ zj,
                                             unsigned short* __restrict__ reps,
                                             float* __restrict__ pos,
                                             float* __restrict__ selfexp,
                                             float* __restrict__ rowsum) {
    int wave = threadIdx.x >> 6, lane = threadIdx.x & 63;
    int k = blockIdx.x * 4 + wave;   // 0..4095
    float4 a = *(const float4*)(zi + (size_t)k * D_DIM + lane * 4);
    float4 b = *(const float4*)(zj + (size_t)k * D_DIM + lane * 4);
    float dii = a.x * a.x + a.y * a.y + a.z * a.z + a.w * a.w;
    float djj = b.x * b.x + b.y * b.y + b.z * b.z + b.w * b.w;
    float dij = a.x * b.x + a.y * b.y + a.z * b.z + a.w * b.w;
#pragma unroll
    for (int m = 1; m < 64; m <<= 1) {
        dii += __shfl_xor(dii, m, 64);
        djj += __shfl_xor(djj, m, 64);
        dij += __shfl_xor(dij, m, 64);
    }
    float si = 1.0f / fmaxf(sqrtf(dii), 1e-12f);
    float sj = 1.0f / fmaxf(sqrtf(djj), 1e-12f);

    unsigned a0 = bf16rne(a.x * si), a1 = bf16rne(a.y * si);
    unsigned a2 = bf16rne(a.z * si), a3 = bf16rne(a.w * si);
    unsigned b0 = bf16rne(b.x * sj), b1 = bf16rne(b.y * sj);
    unsigned b2 = bf16rne(b.z * sj), b3 = bf16rne(b.w * sj);
    {
        uint2 o; o.x = a0 | (a1 << 16); o.y = a2 | (a3 << 16);
        *(uint2*)(reps + (size_t)k * D_DIM + lane * 4) = o;
    }
    {
        uint2 o; o.x = b0 | (b1 << 16); o.y = b2 | (b3 << 16);
        *(uint2*)(reps + (size_t)(k + N_ROWS) * D_DIM + lane * 4) = o;
    }
    float fa0 = bf16val(a0), fa1 = bf16val(a1), fa2 = bf16val(a2), fa3 = bf16val(a3);
    float fb0 = bf16val(b0), fb1 = bf16val(b1), fb2 = bf16val(b2), fb3 = bf16val(b3);
    float sa = fa0 * fa0 + fa1 * fa1 + fa2 * fa2 + fa3 * fa3;
    float sb = fb0 * fb0 + fb1 * fb1 + fb2 * fb2 + fb3 * fb3;
#pragma unroll
    for (int m = 1; m < 64; m <<= 1) {
        sa += __shfl_xor(sa, m, 64);
        sb += __shfl_xor(sb, m, 64);
    }
    if (lane == 0) {
        float p = dij * si * sj * 2.0f;   // /TEMPERATURE
        pos[k] = p;
        pos[k + N_ROWS] = p;
        selfexp[k] = __builtin_amdgcn_exp2f(sa * C_EXP);
        selfexp[k + N_ROWS] = __builtin_amdgcn_exp2f(sb * C_EXP);
    }
    if (threadIdx.x < 8) rowsum[blockIdx.x * 8 + threadIdx.x] = 0.0f;
}

// ---------- K2: R10 inner loop + wrap-balanced symmetry ----------
// Grid 512 = 64 rt x 8 sg. Row-band rt (128 rows) computes 128x128 tiles at
// ct = (rt+s)&63 for s = 4*sg..4*sg+3, plus s=32 when sg==7 && rt<32.
// Coverage: each ordered pair (i,j) exactly once — direct for offsets s in 0..32,
// mirrors (s in 33..63) via col-emission (symmetry: colsum of exp = rowsum of exp^T).
// s=0 (diag tile) emits rows only (covers both orders internally; self via selfexp).
// Inner loop per 64-col sub-tile: R10 verbatim (reg-staged XOR-swizzled LDS B,
// 16x16x32 MFMA 2x4 frags, 2 syncthreads). Col flush: 8 shfl + 64 atomics/sub-tile.
// XCD patch: xcd owns rt in [8*xcd, 8*xcd+8) -> A 0.5MB + B ~2.3MB < 4MB L2.
__global__ __launch_bounds__(256) void kmain(const unsigned short* __restrict__ reps,
                                             float* __restrict__ rowsum) {
    __shared__ __align__(16) char ldsB[64 * 512];   // 32 KiB
    __shared__ float colpart[4][64];                // 1 KiB

    const int tid = threadIdx.x;
    const int wave = tid >> 6, lane = tid & 63;
    const int l15 = lane & 15, lhi = lane >> 4;

    const int xcd = blockIdx.x & 7;
    const int local = blockIdx.x >> 3;          // 0..63
    const int rt = xcd * 8 + (local & 7);       // 0..63
    const int sg = local >> 3;                  // 0..7
    const int ns = (sg == 7 && rt < 32) ? 5 : 4;

    const int rowbaseW = rt * 128 + wave * 32;
    const char* repsb = (const char*)reps;

    // A fragments: 2 row-frags x 8 k-steps, 16B each  (R10 verbatim)
    short8 afrag[2][8];
#pragma unroll
    for (int rf = 0; rf < 2; ++rf) {
        const char* arow = repsb + (size_t)(rowbaseW + rf * 16 + l15) * ROWB;
#pragma unroll
        for (int ks = 0; ks < 8; ++ks)
            afrag[rf][ks] = *(const short8*)(arow + ks * 64 + lhi * 16);
    }

    float rsum[2][4];
#pragma unroll
    for (int rf = 0; rf < 2; ++rf)
#pragma unroll
        for (int r = 0; r < 4; ++r) rsum[rf][r] = 0.0f;

    for (int si = 0; si < ns; ++si) {
        const int s = 4 * sg + si;              // si==4 -> s==32
        const int ct = (rt + s) & 63;
        const bool do_col = (s > 0);            // block-uniform

        for (int sub = 0; sub < 2; ++sub) {
            const int colbase = ct * 128 + sub * 64;

            // stage B tile [64 cols][512 B] with slot XOR-swizzle  (R10 verbatim)
#pragma unroll
            for (int i = 0; i < 8; ++i) {
                int o = tid * 16 + i * 4096;
                int row = o >> 9;
                int slot = (o >> 4) & 31;
                uint4 v = *(const uint4*)(repsb + (size_t)(colbase + row) * ROWB + slot * 16);
                int dslot = slot ^ (row & 7);
                *(uint4*)(ldsB + row * 512 + dslot * 16) = v;
            }
            __syncthreads();

            f32x4 acc[2][4];
#pragma unroll
            for (int rf = 0; rf < 2; ++rf)
#pragma unroll
                for (int cf = 0; cf < 4; ++cf) acc[rf][cf] = (f32x4){0.f, 0.f, 0.f, 0.f};

#pragma unroll
            for (int ks = 0; ks < 8; ++ks) {
                short8 bfr[4];
#pragma unroll
                for (int cf = 0; cf < 4; ++cf) {
                    int col = cf * 16 + l15;
                    int slot = ks * 4 + lhi;
                    int ds = slot ^ (col & 7);
                    bfr[cf] = *(const short8*)(ldsB + col * 512 + ds * 16);
                }
#pragma unroll
                for (int rf = 0; rf < 2; ++rf)
#pragma unroll
                    for (int cf = 0; cf < 4; ++cf)
                        acc[rf][cf] = __builtin_amdgcn_mfma_f32_16x16x32_bf16(
                            afrag[rf][ks], bfr[cf], acc[rf][cf], 0, 0, 0);
            }
            __syncthreads();

            // epilogue: exp once, feed row-partials (regs) + col-partials (per-lane)
            float colsum[4];
#pragma unroll
            for (int cf = 0; cf < 4; ++cf) {
                float cacc = 0.0f;
#pragma unroll
                for (int rf = 0; rf < 2; ++rf) {
                    f32x4 cv = acc[rf][cf];
#pragma unroll
                    for (int r = 0; r < 4; ++r) {
                        float e = __builtin_amdgcn_exp2f(cv[r] * C_EXP);
                        rsum[rf][r] += e;
                        cacc += e;
                    }
                }
                colsum[cf] = cacc;
            }

            if (do_col) {   // block-uniform branch
#pragma unroll
                for (int cf = 0; cf < 4; ++cf) {
                    float v = colsum[cf];
                    v += __shfl_xor(v, 16, 64);
                    v += __shfl_xor(v, 32, 64);
                    if (lane < 16) colpart[wave][cf * 16 + lane] = v;
                }
                __syncthreads();
                if (tid < 64)
                    atomicAdd(&rowsum[colbase + tid],
                              colpart[0][tid] + colpart[1][tid] +
                              colpart[2][tid] + colpart[3][tid]);
            }
        }
    }

    // row-partials: reduce 16 lanes sharing each row, one atomic per row  (R10 verbatim)
#pragma unroll
    for (int rf = 0; rf < 2; ++rf)
#pragma unroll
        for (int r = 0; r < 4; ++r) {
            float s = rsum[rf][r];
            s += __shfl_xor(s, 1, 64);
            s += __shfl_xor(s, 2, 64);
            s += __shfl_xor(s, 4, 64);
            s += __shfl_xor(s, 8, 64);
            if (l15 == 0)
                atomicAdd(&rowsum[rowbaseW + rf * 16 + lhi * 4 + r], s);
        }
}

// ---------- K3: loss = mean(log(rowsum - selfexp) - pos) ----------
__global__ __launch_bounds__(1024) void kfinal(const float* __restrict__ rowsum,
                                               const float* __restrict__ pos,
                                               const float* __restrict__ selfexp,
                                               float* __restrict__ out) {
    __shared__ float red[16];
    float local = 0.0f;
    for (int r = threadIdx.x; r < TWO_N; r += 1024)
        local += __builtin_amdgcn_logf(rowsum[r] - selfexp[r]) * 0.6931471805599453f - pos[r];
#pragma unroll
    for (int m = 1; m < 64; m <<= 1) local += __shfl_xor(local, m, 64);
    if ((threadIdx.x & 63) == 0) red[threadIdx.x >> 6] = local;
    __syncthreads();
    if (threadIdx.x == 0) {
        float t = 0.0f;
#pragma unroll
        for (int i = 0; i < 16; ++i) t += red[i];
        out[0] = t * (1.0f / (float)TWO_N);
    }
}

extern "C" void kernel_launch(void* const* d_in, const int* in_sizes, int n_in,
                              void* d_out, int out_size, void* d_ws, size_t ws_size,
                              hipStream_t stream) {
    const float* zi = (const float*)d_in[0];
    const float* zj = (const float*)d_in[1];
    float* out = (float*)d_out;

    unsigned short* reps = (unsigned short*)d_ws;                       // 4 MiB
    float* rowsum = (float*)((char*)d_ws + (size_t)TWO_N * D_DIM * 2);  // 32 KiB
    float* pos = rowsum + TWO_N;                                        // 32 KiB
    float* selfexp = pos + TWO_N;                                       // 32 KiB

    kprep<<<1024, 256, 0, stream>>>(zi, zj, reps, pos, selfexp, rowsum);
    kmain<<<512, 256, 0, stream>>>(reps, rowsum);
    kfinal<<<1, 1024, 0, stream>>>(rowsum, pos, selfexp, out);
}